// Round 2
// baseline (2620.232 us; speedup 1.0000x reference)
//
#include <hip/hip_runtime.h>
#include <stdint.h>

// Round 5: FPS tail collapse via monotonic-key LDS atomicMax (selection exact).
//  - Cross-wave argmax: each wave's winner LANE builds a 64-bit key
//        (s << 45) | (float_bits(lv) << 13) | (8191 - index)
//    and atomicMax's it into s_key[s&1]. Distances >= 0 -> float bits are
//    order-preserving unsigned; (8191-index) makes ties resolve to LOWEST index
//    (jnp.argmax semantics); iteration tag s makes fresh keys dominate stale ones
//    -> no reset, single barrier, parity slots kill the read(s)/atomic(s+1) race;
//    barrier lgkmcnt-drain orders atomic(s+2) after read(s).
//  - Removes entire phase-2 (DPP reduce + 2 ballots + 3 readlanes + s_v/s_i round
//    trip): post-barrier tail is now ds_read_b64 -> extract bi -> centroid ds_read.
//  - Phase 1 unchanged from validated Round 4 (packed v2f core, contraction-free,
//    descending first-index scan).
//  - group_kernel: XCD-locality swizzle gb=(bx&7)*2048+(bx>>3) pins batch b to
//    XCD b -> 4MB points table becomes L2-resident per XCD. Math untouched.

#define NBATCH 8
#define NPTS   8192
#define NCH    128
#define NGROUP 2048
#define NK     24
#define ROWLEN (2 * NCH + 3)   // 259

#define FPS_T  512
#define PPT    16              // points per thread (8 pairs)

typedef float v2f __attribute__((ext_vector_type(2)));

__device__ __forceinline__ float sq3_nofma(float dx, float dy, float dz) {
#pragma clang fp contract(off)
  return dx * dx + dy * dy + dz * dz;
}

// numpy einsum contracted inner loop: acc = a0*b0; acc = fma(a1,b1,acc); acc = fma(a2,b2,acc)
__device__ __forceinline__ float dot3_fma(float ax, float ay, float az,
                                          float bx, float by, float bz) {
  float acc = __fmul_rn(ax, bx);
  acc = __fmaf_rn(ay, by, acc);
  acc = __fmaf_rn(az, bz, acc);
  return acc;
}

__device__ __forceinline__ float ballquery_sqr(float srcSq, float dstSq, float dot) {
#pragma clang fp contract(off)
  return (srcSq + dstSq) - 2.0f * dot;
}

template <int CTRL>
__device__ __forceinline__ float maxdpp(float v) {
  int s = __builtin_amdgcn_update_dpp(__builtin_bit_cast(int, v),
                                      __builtin_bit_cast(int, v),
                                      CTRL, 0xF, 0xF, false);
  return fmaxf(v, __builtin_bit_cast(float, s));
}

__device__ __forceinline__ float readlane_f(float v, int lane) {
  return __builtin_bit_cast(float,
      __builtin_amdgcn_readlane(__builtin_bit_cast(int, v), lane));
}

__global__ __launch_bounds__(FPS_T) void fps_kernel(const float* __restrict__ xyz,
                                                    int* __restrict__ fps_idx) {
  const int b = blockIdx.x;
  const int t = threadIdx.x;
  const int lane = t & 63;
  const float* xb = xyz + (size_t)b * NPTS * 3;

  __shared__ float s_xyz[NPTS * 3];            // 96 KB: centroid gather source
  __shared__ unsigned long long s_key[2];      // parity-slotted monotonic argmax key

  // stage xyz -> LDS (coalesced float4); init key slots
  {
    const float4* src4 = (const float4*)xb;
    float4* dst4 = (float4*)s_xyz;
    for (int i = t; i < (NPTS * 3) / 4; i += FPS_T) dst4[i] = src4[i];
  }
  if (t == 0) { s_key[0] = 0ull; s_key[1] = 0ull; }

  // thread t owns CONTIGUOUS points [16t, 16t+16): lane order == index order,
  // wave order == index order -> ballot+ctz keeps np.argmax first-index tie-break.
  const int base = t * PPT;
  v2f px[8], py[8], pz[8], d2[8];
#pragma unroll
  for (int j = 0; j < 8; ++j) {
    const int n0 = base + 2 * j;
    px[j].x = xb[n0 * 3 + 0]; py[j].x = xb[n0 * 3 + 1]; pz[j].x = xb[n0 * 3 + 2];
    px[j].y = xb[n0 * 3 + 3]; py[j].y = xb[n0 * 3 + 4]; pz[j].y = xb[n0 * 3 + 5];
    d2[j].x = 1e10f; d2[j].y = 1e10f;
  }

  float cx = xb[0], cy = xb[1], cz = xb[2];   // centroid 0 = point 0
  if (t == 0) fps_idx[b * NGROUP + 0] = 0;

  __syncthreads();   // one-time: orders s_key init (and staging) before iteration 1

  for (int s = 1; s < NGROUP; ++s) {
    // ---- phase 1: packed min-update + value max (exact, contraction-free) ----
    float lv = -1.0f;
#pragma unroll
    for (int j = 0; j < 8; ++j) {
      v2f dx, dy, dz, dd, nd;
      {
#pragma clang fp contract(off)
        dx = px[j] - cx;                    // v_pk_add_f32 (neg)
        dy = py[j] - cy;
        dz = pz[j] - cz;
        dd = dx * dx + dy * dy + dz * dz;   // 3x pk_mul + 2x pk_add, never fused
      }
      nd.x = fminf(d2[j].x, dd.x);
      nd.y = fminf(d2[j].y, dd.y);
      d2[j] = nd;
      lv = fmaxf(fmaxf(nd.x, nd.y), lv);    // v_max3_f32
    }
    // first-index recovery: descending overwrite -> lowest matching index wins
    int kk = 0;
#pragma unroll
    for (int j = 7; j >= 0; --j) {
      if (d2[j].y == lv) kk = 2 * j + 1;
      if (d2[j].x == lv) kk = 2 * j;
    }
    const int li = base + kk;

    // ---- wave argmax via DPP (value max, then ballot for first index) ----
    float v = lv;
    v = maxdpp<0x111>(v);   // row_shr:1
    v = maxdpp<0x112>(v);   // row_shr:2
    v = maxdpp<0x114>(v);   // row_shr:4
    v = maxdpp<0x118>(v);   // row_shr:8
    v = maxdpp<0x142>(v);   // row_bcast15
    v = maxdpp<0x143>(v);   // row_bcast31
    const float wmax = readlane_f(v, 63);
    const unsigned long long m = __ballot(lv == wmax);
    const int wl = (int)__builtin_ctzll(m);   // lowest lane = lowest index

    // winner lane publishes its own (value, index) as a monotonic key
    if (lane == wl) {
      const unsigned long long key =
          ((unsigned long long)(unsigned)s << 45) |
          ((unsigned long long)__builtin_bit_cast(unsigned, lv) << 13) |
          (unsigned long long)(unsigned)(8191 - li);
      atomicMax(&s_key[s & 1], key);
    }
    __syncthreads();   // the ONLY barrier: atomics(s) -> reads(s); drains lgkm

    const unsigned long long gk = s_key[s & 1];
    const int bi = 8191 - (int)(gk & 0x1fffu);

    if (t == 0) fps_idx[b * NGROUP + s] = bi;

    // next centroid coords: broadcast LDS read
    const int b3 = bi * 3;
    cx = s_xyz[b3 + 0];
    cy = s_xyz[b3 + 1];
    cz = s_xyz[b3 + 2];
  }
}

__global__ __launch_bounds__(256) void group_kernel(const float* __restrict__ xyz,
                                                    const float* __restrict__ points,
                                                    const int* __restrict__ fps_idx,
                                                    float* __restrict__ out) {
  const int bx = blockIdx.x;
  const int gb = ((bx & 7) << 11) | (bx >> 3);   // XCD b <- batch b (L2-resident gathers)
  const int b = gb >> 11;
  const int tid = threadIdx.x;
  const float* xb = xyz + (size_t)b * NPTS * 3;
  const float* pb = points + (size_t)b * NPTS * NCH;

  __shared__ int s_idx[NK];

  const int a_idx = fps_idx[gb];
  const float cx = xb[a_idx * 3 + 0];
  const float cy = xb[a_idx * 3 + 1];
  const float cz = xb[a_idx * 3 + 2];
  const float srcSq = sq3_nofma(cx, cy, cz);
  const float R2 = (float)(0.2 * 0.2);

  if (tid < 64) {
    int cnt = 0;
    int first = 0;
    const unsigned long long below = ((unsigned long long)1 << tid) - 1ull;
    for (int chunk = 0; chunk < NPTS / 128; ++chunk) {
      const int n0 = (chunk << 7) + (tid << 1);        // 2 points per lane
      const float* p = xb + (size_t)n0 * 3;            // 24B-aligned
      const float2 A = *(const float2*)(p + 0);        // x0 y0
      const float2 Bv = *(const float2*)(p + 2);       // z0 x1
      const float2 C = *(const float2*)(p + 4);        // y1 z1
      const float x0 = A.x, y0 = A.y, z0 = Bv.x;
      const float x1 = Bv.y, y1 = C.x, z1 = C.y;

      const float sqr0 = ballquery_sqr(srcSq, sq3_nofma(x0, y0, z0),
                                       dot3_fma(cx, cy, cz, x0, y0, z0));
      const float sqr1 = ballquery_sqr(srcSq, sq3_nofma(x1, y1, z1),
                                       dot3_fma(cx, cy, cz, x1, y1, z1));
      const bool ok0 = !(sqr0 > R2);
      const bool ok1 = !(sqr1 > R2);
      const unsigned long long m0 = __ballot(ok0);
      const unsigned long long m1 = __ballot(ok1);
      if (cnt == 0 && (m0 | m1)) {
        const int f0 = m0 ? (int)__builtin_ctzll(m0) : 64;
        const int f1 = m1 ? (int)__builtin_ctzll(m1) : 64;
        first = (f0 <= f1) ? ((chunk << 7) + 2 * f0) : ((chunk << 7) + 2 * f1 + 1);
      }
      const int p0 = cnt + (int)__popcll(m0 & below) + (int)__popcll(m1 & below);
      const int p1 = p0 + (ok0 ? 1 : 0);
      if (ok0 && p0 < NK) s_idx[p0] = n0;
      if (ok1 && p1 < NK) s_idx[p1] = n0 + 1;
      cnt += (int)__popcll(m0) + (int)__popcll(m1);
      if (cnt >= NK) break;
    }
    if (tid >= cnt && tid < NK) s_idx[tid] = first;  // pad with first in-radius index
  }
  __syncthreads();

  // output 0: new_xyz (exact copy of the centroid row)
  if (tid == 0) {
    float* onx = out + (size_t)gb * 3;
    onx[0] = cx; onx[1] = cy; onx[2] = cz;
  }

  // output 1: new_points rows — [points[idx](128) | xyz[idx](3) | points[anchor](128)]
  float* op = out + (size_t)NBATCH * NGROUP * 3 + (size_t)gb * (NK * ROWLEN);
  const float* anchor = pb + (size_t)a_idx * NCH;
  for (int e = tid; e < NK * ROWLEN; e += 256) {
    const int k = e / ROWLEN;
    const int c = e - k * ROWLEN;
    const int si = s_idx[k];
    float v;
    if (c < NCH)            v = pb[(size_t)si * NCH + c];
    else if (c < NCH + 3)   v = xb[si * 3 + (c - NCH)];
    else                    v = anchor[c - (NCH + 3)];
    op[e] = v;
  }
}

extern "C" void kernel_launch(void* const* d_in, const int* in_sizes, int n_in,
                              void* d_out, int out_size, void* d_ws, size_t ws_size,
                              hipStream_t stream) {
  const float* xyz = (const float*)d_in[0];
  const float* points = (const float*)d_in[1];
  float* out = (float*)d_out;
  int* fps_idx = (int*)d_ws;  // 8*2048 ints

  fps_kernel<<<dim3(NBATCH), dim3(FPS_T), 0, stream>>>(xyz, fps_idx);
  group_kernel<<<dim3(NBATCH * NGROUP), dim3(256), 0, stream>>>(xyz, points, fps_idx, out);
}

// Round 4
// 2133.973 us; speedup vs baseline: 1.2279x; 1.2279x over previous
//
#include <hip/hip_runtime.h>
#include <stdint.h>

// Round 6 resubmit (R3 bench was GPUAcquisitionTimeout — never ran).
//  - Phase 2: lane0/wave publishes (wmax,wli) as ONE ds_write_b64; after the
//    barrier ALL threads read the 8 pairs via 4 broadcast ds_read_b128 and run a
//    uniform 7-step strict-> scan (cmp + bitwise cndmask) -> no DPP hazards,
//    no ballot/readlane post-barrier. Lowest-wave-on-tie == lowest index (wave
//    order == index order), exact jnp.argmax semantics.
//  - Phase 1 bit-identical to validated R4 (packed v2f, contraction-free,
//    descending first-index scan). Single barrier + parity-buffered pairs.
//  - group_kernel: keep XCD swizzle; epilogue vectorized: points/anchor parts
//    copied as float4 (dword-aligned packed 16B stores), xyz part scalar.
//    Ball-query scan + s_idx logic untouched (validated).

#define NBATCH 8
#define NPTS   8192
#define NCH    128
#define NGROUP 2048
#define NK     24
#define ROWLEN (2 * NCH + 3)   // 259

#define FPS_T  512
#define PPT    16              // points per thread (8 pairs)

typedef float v2f __attribute__((ext_vector_type(2)));

struct __attribute__((packed, aligned(4))) f4s { float x, y, z, w; };  // dword-aligned 16B

__device__ __forceinline__ float sq3_nofma(float dx, float dy, float dz) {
#pragma clang fp contract(off)
  return dx * dx + dy * dy + dz * dz;
}

// numpy einsum contracted inner loop: acc = a0*b0; acc = fma(a1,b1,acc); acc = fma(a2,b2,acc)
__device__ __forceinline__ float dot3_fma(float ax, float ay, float az,
                                          float bx, float by, float bz) {
  float acc = __fmul_rn(ax, bx);
  acc = __fmaf_rn(ay, by, acc);
  acc = __fmaf_rn(az, bz, acc);
  return acc;
}

__device__ __forceinline__ float ballquery_sqr(float srcSq, float dstSq, float dot) {
#pragma clang fp contract(off)
  return (srcSq + dstSq) - 2.0f * dot;
}

template <int CTRL>
__device__ __forceinline__ float maxdpp(float v) {
  int s = __builtin_amdgcn_update_dpp(__builtin_bit_cast(int, v),
                                      __builtin_bit_cast(int, v),
                                      CTRL, 0xF, 0xF, false);
  return fmaxf(v, __builtin_bit_cast(float, s));
}

__device__ __forceinline__ float readlane_f(float v, int lane) {
  return __builtin_bit_cast(float,
      __builtin_amdgcn_readlane(__builtin_bit_cast(int, v), lane));
}

__global__ __launch_bounds__(FPS_T) void fps_kernel(const float* __restrict__ xyz,
                                                    int* __restrict__ fps_idx) {
  const int b = blockIdx.x;
  const int t = threadIdx.x;
  const int lane = t & 63;
  const int w = t >> 6;                 // 8 waves
  const float* xb = xyz + (size_t)b * NPTS * 3;

  __shared__ float s_xyz[NPTS * 3];     // 96 KB: centroid gather source
  // per-wave (value, index) pairs, parity-buffered; u64 write == {v lo, i hi}
  union pair_t { struct { float v; int i; }; unsigned long long u; };
  __shared__ __align__(16) pair_t s_p[2][8];

  // stage xyz -> LDS (coalesced float4; consumed only after first in-loop barrier)
  {
    const float4* src4 = (const float4*)xb;
    float4* dst4 = (float4*)s_xyz;
    for (int i = t; i < (NPTS * 3) / 4; i += FPS_T) dst4[i] = src4[i];
  }

  // thread t owns CONTIGUOUS points [16t, 16t+16): lane order == index order,
  // wave order == index order -> ballot+ctz keeps np.argmax first-index tie-break.
  const int base = t * PPT;
  v2f px[8], py[8], pz[8], d2[8];
#pragma unroll
  for (int j = 0; j < 8; ++j) {
    const int n0 = base + 2 * j;
    px[j].x = xb[n0 * 3 + 0]; py[j].x = xb[n0 * 3 + 1]; pz[j].x = xb[n0 * 3 + 2];
    px[j].y = xb[n0 * 3 + 3]; py[j].y = xb[n0 * 3 + 4]; pz[j].y = xb[n0 * 3 + 5];
    d2[j].x = 1e10f; d2[j].y = 1e10f;
  }

  float cx = xb[0], cy = xb[1], cz = xb[2];   // centroid 0 = point 0
  if (t == 0) fps_idx[b * NGROUP + 0] = 0;

  for (int s = 1; s < NGROUP; ++s) {
    const int p = s & 1;

    // ---- phase 1: packed min-update + value max (exact, contraction-free) ----
    float lv = -1.0f;
#pragma unroll
    for (int j = 0; j < 8; ++j) {
      v2f dx, dy, dz, dd, nd;
      {
#pragma clang fp contract(off)
        dx = px[j] - cx;                    // v_pk_add_f32 (neg)
        dy = py[j] - cy;
        dz = pz[j] - cz;
        dd = dx * dx + dy * dy + dz * dz;   // 3x pk_mul + 2x pk_add, never fused
      }
      nd.x = fminf(d2[j].x, dd.x);
      nd.y = fminf(d2[j].y, dd.y);
      d2[j] = nd;
      lv = fmaxf(fmaxf(nd.x, nd.y), lv);    // v_max3_f32
    }
    // first-index recovery: descending overwrite -> lowest matching index wins
    int kk = 0;
#pragma unroll
    for (int j = 7; j >= 0; --j) {
      if (d2[j].y == lv) kk = 2 * j + 1;
      if (d2[j].x == lv) kk = 2 * j;
    }
    const int li = base + kk;

    // ---- wave argmax via DPP (value max, then ballot for first index) ----
    float v = lv;
    v = maxdpp<0x111>(v);   // row_shr:1
    v = maxdpp<0x112>(v);   // row_shr:2
    v = maxdpp<0x114>(v);   // row_shr:4
    v = maxdpp<0x118>(v);   // row_shr:8
    v = maxdpp<0x142>(v);   // row_bcast15
    v = maxdpp<0x143>(v);   // row_bcast31
    const float wmax = readlane_f(v, 63);
    const unsigned long long m = __ballot(lv == wmax);
    const int wl = (int)__builtin_ctzll(m);            // lowest lane = lowest index
    const int wli = __builtin_amdgcn_readlane(li, wl);
    if (lane == 0) {
      s_p[p][w].u = ((unsigned long long)(unsigned)wli << 32) |
                    (unsigned long long)__builtin_bit_cast(unsigned, wmax);
    }
    __syncthreads();   // the ONLY barrier: orders buf[p] write->read AND buf[p^1] reuse

    // ---- phase 2: uniform in-register scan of the 8 pairs (no cross-lane ops) ----
    const float4* q = (const float4*)&s_p[p][0];   // broadcast reads, 2 pairs each
    const float4 q0 = q[0], q1 = q[1], q2 = q[2], q3 = q[3];
    float bv = q0.x;
    float biF = q0.y;   // index carried as raw bits; cndmask is bitwise-safe
    {
      const float vv[7] = { q0.z, q1.x, q1.z, q2.x, q2.z, q3.x, q3.z };
      const float ii[7] = { q0.w, q1.y, q1.w, q2.y, q2.w, q3.y, q3.w };
#pragma unroll
      for (int k = 0; k < 7; ++k) {
        const bool gt = vv[k] > bv;        // strict > : lowest wave wins ties
        bv  = gt ? vv[k] : bv;
        biF = gt ? ii[k] : biF;
      }
    }
    const int bi = __builtin_bit_cast(int, biF);

    if (t == 0) fps_idx[b * NGROUP + s] = bi;

    // next centroid coords: broadcast LDS read
    const int b3 = bi * 3;
    cx = s_xyz[b3 + 0];
    cy = s_xyz[b3 + 1];
    cz = s_xyz[b3 + 2];
  }
}

__global__ __launch_bounds__(256) void group_kernel(const float* __restrict__ xyz,
                                                    const float* __restrict__ points,
                                                    const int* __restrict__ fps_idx,
                                                    float* __restrict__ out) {
  const int bx = blockIdx.x;
  const int gb = ((bx & 7) << 11) | (bx >> 3);   // XCD b <- batch b (L2-resident gathers)
  const int b = gb >> 11;
  const int tid = threadIdx.x;
  const float* xb = xyz + (size_t)b * NPTS * 3;
  const float* pb = points + (size_t)b * NPTS * NCH;

  __shared__ int s_idx[NK];

  const int a_idx = fps_idx[gb];
  const float cx = xb[a_idx * 3 + 0];
  const float cy = xb[a_idx * 3 + 1];
  const float cz = xb[a_idx * 3 + 2];
  const float srcSq = sq3_nofma(cx, cy, cz);
  const float R2 = (float)(0.2 * 0.2);

  if (tid < 64) {
    int cnt = 0;
    int first = 0;
    const unsigned long long below = ((unsigned long long)1 << tid) - 1ull;
    for (int chunk = 0; chunk < NPTS / 128; ++chunk) {
      const int n0 = (chunk << 7) + (tid << 1);        // 2 points per lane
      const float* p = xb + (size_t)n0 * 3;            // 24B-aligned
      const float2 A = *(const float2*)(p + 0);        // x0 y0
      const float2 Bv = *(const float2*)(p + 2);       // z0 x1
      const float2 C = *(const float2*)(p + 4);        // y1 z1
      const float x0 = A.x, y0 = A.y, z0 = Bv.x;
      const float x1 = Bv.y, y1 = C.x, z1 = C.y;

      const float sqr0 = ballquery_sqr(srcSq, sq3_nofma(x0, y0, z0),
                                       dot3_fma(cx, cy, cz, x0, y0, z0));
      const float sqr1 = ballquery_sqr(srcSq, sq3_nofma(x1, y1, z1),
                                       dot3_fma(cx, cy, cz, x1, y1, z1));
      const bool ok0 = !(sqr0 > R2);
      const bool ok1 = !(sqr1 > R2);
      const unsigned long long m0 = __ballot(ok0);
      const unsigned long long m1 = __ballot(ok1);
      if (cnt == 0 && (m0 | m1)) {
        const int f0 = m0 ? (int)__builtin_ctzll(m0) : 64;
        const int f1 = m1 ? (int)__builtin_ctzll(m1) : 64;
        first = (f0 <= f1) ? ((chunk << 7) + 2 * f0) : ((chunk << 7) + 2 * f1 + 1);
      }
      const int p0 = cnt + (int)__popcll(m0 & below) + (int)__popcll(m1 & below);
      const int p1 = p0 + (ok0 ? 1 : 0);
      if (ok0 && p0 < NK) s_idx[p0] = n0;
      if (ok1 && p1 < NK) s_idx[p1] = n0 + 1;
      cnt += (int)__popcll(m0) + (int)__popcll(m1);
      if (cnt >= NK) break;
    }
    if (tid >= cnt && tid < NK) s_idx[tid] = first;  // pad with first in-radius index
  }
  __syncthreads();

  // output 0: new_xyz (exact copy of the centroid row)
  if (tid == 0) {
    float* onx = out + (size_t)gb * 3;
    onx[0] = cx; onx[1] = cy; onx[2] = cz;
  }

  // output 1: new_points rows — [points[idx](128) | xyz[idx](3) | points[anchor](128)]
  // Row stride 259 floats -> rows are only dword-aligned; f4s stores are align(4).
  float* op = out + (size_t)NBATCH * NGROUP * 3 + (size_t)gb * (NK * ROWLEN);
  const float* anchor = pb + (size_t)a_idx * NCH;

  // points part: 24 rows x 32 float4  (768 = 3 * 256)
#pragma unroll
  for (int it = 0; it < 3; ++it) {
    const int vidx = tid + (it << 8);
    const int k = vidx >> 5;
    const int c4 = vidx & 31;
    const int si = s_idx[k];
    const f4s val = *(const f4s*)(pb + (size_t)si * NCH + (c4 << 2));
    *(f4s*)(op + k * ROWLEN + (c4 << 2)) = val;
  }
  // anchor part: 24 rows x 32 float4
#pragma unroll
  for (int it = 0; it < 3; ++it) {
    const int vidx = tid + (it << 8);
    const int k = vidx >> 5;
    const int c4 = vidx & 31;
    const f4s val = *(const f4s*)(anchor + (c4 << 2));
    *(f4s*)(op + k * ROWLEN + (NCH + 3) + (c4 << 2)) = val;
  }
  // xyz part: 24 rows x 3 floats
  if (tid < NK * 3) {
    const int k = tid / 3;
    const int r = tid - k * 3;
    const int si = s_idx[k];
    op[k * ROWLEN + NCH + r] = xb[si * 3 + r];
  }
}

extern "C" void kernel_launch(void* const* d_in, const int* in_sizes, int n_in,
                              void* d_out, int out_size, void* d_ws, size_t ws_size,
                              hipStream_t stream) {
  const float* xyz = (const float*)d_in[0];
  const float* points = (const float*)d_in[1];
  float* out = (float*)d_out;
  int* fps_idx = (int*)d_ws;  // 8*2048 ints

  fps_kernel<<<dim3(NBATCH), dim3(FPS_T), 0, stream>>>(xyz, fps_idx);
  group_kernel<<<dim3(NBATCH * NGROUP), dim3(256), 0, stream>>>(xyz, points, fps_idx, out);
}

// Round 6
// 2034.372 us; speedup vs baseline: 1.2880x; 1.0490x over previous
//
#include <hip/hip_runtime.h>
#include <stdint.h>

// Round 7 resubmit (R5 bench was GPUAcquisitionTimeout — never ran).
// Fused producer-consumer — hide group_kernel under the serial FPS.
//  - ONE kernel, 256 blocks x 512 threads. Blocks 0-7: fps role (bit-identical
//    R6 internals). Blocks 8-255: persistent group role, 2 groups/iter (two
//    256-thread halves), g-ascending schedule synced to fps production.
//  - Sync: fps_idx pre-poisoned to -1 (hipMemsetAsync, capture-safe); fps
//    publishes via relaxed agent-scope atomic store; consumers spin on relaxed
//    agent-scope atomic load until != -1. Payload IS the polled word -> no
//    fences needed; device-scope atomics are cross-XCD safe (G16/G12).
//  - Deadlock-free by construction: every block allocates ~98.8 KB LDS -> HW
//    fits at most 1 block/CU -> all 256 blocks resident regardless of dispatch
//    order; fps blocks depend on nothing.
//  - Group internals = validated R6 (ball-query scan, ordered compaction, f4s
//    vectorized epilogue); batch affinity b=(blk-8)&7 keeps XCD L2 locality.

#define NBATCH 8
#define NPTS   8192
#define NCH    128
#define NGROUP 2048
#define NK     24
#define ROWLEN (2 * NCH + 3)   // 259

#define FPS_T   512
#define PPT     16             // fps: points per thread (8 pairs)
#define GBLOCKS 248            // group blocks (31 per batch)
#define GSLOTS  62             // 2 * (GBLOCKS/8) group slots per batch
#define GITERS  34             // ceil(NGROUP / GSLOTS)

typedef float v2f __attribute__((ext_vector_type(2)));

struct __attribute__((packed, aligned(4))) f4s { float x, y, z, w; };  // dword-aligned 16B

__device__ __forceinline__ float sq3_nofma(float dx, float dy, float dz) {
#pragma clang fp contract(off)
  return dx * dx + dy * dy + dz * dz;
}

// numpy einsum contracted inner loop: acc = a0*b0; acc = fma(a1,b1,acc); acc = fma(a2,b2,acc)
__device__ __forceinline__ float dot3_fma(float ax, float ay, float az,
                                          float bx, float by, float bz) {
  float acc = __fmul_rn(ax, bx);
  acc = __fmaf_rn(ay, by, acc);
  acc = __fmaf_rn(az, bz, acc);
  return acc;
}

__device__ __forceinline__ float ballquery_sqr(float srcSq, float dstSq, float dot) {
#pragma clang fp contract(off)
  return (srcSq + dstSq) - 2.0f * dot;
}

template <int CTRL>
__device__ __forceinline__ float maxdpp(float v) {
  int s = __builtin_amdgcn_update_dpp(__builtin_bit_cast(int, v),
                                      __builtin_bit_cast(int, v),
                                      CTRL, 0xF, 0xF, false);
  return fmaxf(v, __builtin_bit_cast(float, s));
}

__device__ __forceinline__ float readlane_f(float v, int lane) {
  return __builtin_bit_cast(float,
      __builtin_amdgcn_readlane(__builtin_bit_cast(int, v), lane));
}

__global__ __launch_bounds__(FPS_T) void fused_kernel(const float* __restrict__ xyz,
                                                      const float* __restrict__ points,
                                                      int* __restrict__ fps_idx,
                                                      float* __restrict__ out) {
  const int t = threadIdx.x;

  // Static LDS (allocated per block; ~98.8 KB -> exactly 1 block/CU).
  __shared__ float s_xyz[NPTS * 3];     // fps: centroid gather source
  union pair_t { struct { float v; int i; }; unsigned long long u; };
  __shared__ __align__(16) pair_t s_p[2][8];
  __shared__ int s_aidx[2];             // group: per-half anchor index
  __shared__ int s_idx2[2][NK];         // group: per-half ball-query indices

  if (blockIdx.x < NBATCH) {
    // ======================= FPS role (R6 internals) =======================
    const int b = blockIdx.x;
    const int lane = t & 63;
    const int w = t >> 6;               // 8 waves
    const float* xb = xyz + (size_t)b * NPTS * 3;

    {
      const float4* src4 = (const float4*)xb;
      float4* dst4 = (float4*)s_xyz;
      for (int i = t; i < (NPTS * 3) / 4; i += FPS_T) dst4[i] = src4[i];
    }

    // thread t owns CONTIGUOUS points [16t, 16t+16): lane order == index order,
    // wave order == index order -> ballot+ctz keeps np.argmax first-index tie-break.
    const int base = t * PPT;
    v2f px[8], py[8], pz[8], d2[8];
#pragma unroll
    for (int j = 0; j < 8; ++j) {
      const int n0 = base + 2 * j;
      px[j].x = xb[n0 * 3 + 0]; py[j].x = xb[n0 * 3 + 1]; pz[j].x = xb[n0 * 3 + 2];
      px[j].y = xb[n0 * 3 + 3]; py[j].y = xb[n0 * 3 + 4]; pz[j].y = xb[n0 * 3 + 5];
      d2[j].x = 1e10f; d2[j].y = 1e10f;
    }

    float cx = xb[0], cy = xb[1], cz = xb[2];   // centroid 0 = point 0
    if (t == 0)
      __hip_atomic_store(&fps_idx[b * NGROUP + 0], 0,
                         __ATOMIC_RELAXED, __HIP_MEMORY_SCOPE_AGENT);

    for (int s = 1; s < NGROUP; ++s) {
      const int p = s & 1;

      // ---- phase 1: packed min-update + value max (exact, contraction-free) ----
      float lv = -1.0f;
#pragma unroll
      for (int j = 0; j < 8; ++j) {
        v2f dx, dy, dz, dd, nd;
        {
#pragma clang fp contract(off)
          dx = px[j] - cx;                    // v_pk_add_f32 (neg)
          dy = py[j] - cy;
          dz = pz[j] - cz;
          dd = dx * dx + dy * dy + dz * dz;   // 3x pk_mul + 2x pk_add, never fused
        }
        nd.x = fminf(d2[j].x, dd.x);
        nd.y = fminf(d2[j].y, dd.y);
        d2[j] = nd;
        lv = fmaxf(fmaxf(nd.x, nd.y), lv);    // v_max3_f32
      }
      // first-index recovery: descending overwrite -> lowest matching index wins
      int kk = 0;
#pragma unroll
      for (int j = 7; j >= 0; --j) {
        if (d2[j].y == lv) kk = 2 * j + 1;
        if (d2[j].x == lv) kk = 2 * j;
      }
      const int li = base + kk;

      // ---- wave argmax via DPP (value max, then ballot for first index) ----
      float v = lv;
      v = maxdpp<0x111>(v);   // row_shr:1
      v = maxdpp<0x112>(v);   // row_shr:2
      v = maxdpp<0x114>(v);   // row_shr:4
      v = maxdpp<0x118>(v);   // row_shr:8
      v = maxdpp<0x142>(v);   // row_bcast15
      v = maxdpp<0x143>(v);   // row_bcast31
      const float wmax = readlane_f(v, 63);
      const unsigned long long m = __ballot(lv == wmax);
      const int wl = (int)__builtin_ctzll(m);            // lowest lane = lowest index
      const int wli = __builtin_amdgcn_readlane(li, wl);
      if (lane == 0) {
        s_p[p][w].u = ((unsigned long long)(unsigned)wli << 32) |
                      (unsigned long long)__builtin_bit_cast(unsigned, wmax);
      }
      __syncthreads();   // the ONLY barrier: orders buf[p] write->read AND buf[p^1] reuse

      // ---- phase 2: uniform in-register scan of the 8 pairs ----
      const float4* q = (const float4*)&s_p[p][0];   // broadcast reads, 2 pairs each
      const float4 q0 = q[0], q1 = q[1], q2 = q[2], q3 = q[3];
      float bv = q0.x;
      float biF = q0.y;   // index carried as raw bits; cndmask is bitwise-safe
      {
        const float vv[7] = { q0.z, q1.x, q1.z, q2.x, q2.z, q3.x, q3.z };
        const float ii[7] = { q0.w, q1.y, q1.w, q2.y, q2.w, q3.y, q3.w };
#pragma unroll
        for (int k = 0; k < 7; ++k) {
          const bool gt = vv[k] > bv;        // strict > : lowest wave wins ties
          bv  = gt ? vv[k] : bv;
          biF = gt ? ii[k] : biF;
        }
      }
      const int bi = __builtin_bit_cast(int, biF);

      if (t == 0)
        __hip_atomic_store(&fps_idx[b * NGROUP + s], bi,
                           __ATOMIC_RELAXED, __HIP_MEMORY_SCOPE_AGENT);

      // next centroid coords: broadcast LDS read
      const int b3 = bi * 3;
      cx = s_xyz[b3 + 0];
      cy = s_xyz[b3 + 1];
      cz = s_xyz[b3 + 2];
    }
    return;
  }

  // ======================= group role (persistent) =======================
  const int gs = blockIdx.x - NBATCH;   // 0..247
  const int b = gs & 7;                 // batch (== XCD affinity, approx)
  const int sb = gs >> 3;               // 0..30
  const int h = t >> 8;                 // half (0/1)
  const int htid = t & 255;
  const float* xb = xyz + (size_t)b * NPTS * 3;
  const float* pb = points + (size_t)b * NPTS * NCH;
  const float R2 = (float)(0.2 * 0.2);

  for (int i = 0; i < GITERS; ++i) {
    const int g = i * GSLOTS + sb * 2 + h;
    const bool act = g < NGROUP;
    const int gb = (b << 11) | (g & 2047);

    // spin until fps produced this group's anchor index (payload == polled word)
    if (htid == 0 && act) {
      int v;
      while ((v = __hip_atomic_load(&fps_idx[gb], __ATOMIC_RELAXED,
                                    __HIP_MEMORY_SCOPE_AGENT)) == -1)
        __builtin_amdgcn_s_sleep(8);
      s_aidx[h] = v;
    }
    __syncthreads();

    int a_idx = 0;
    float cx = 0.f, cy = 0.f, cz = 0.f, srcSq = 0.f;
    if (act) {
      a_idx = s_aidx[h];
      cx = xb[a_idx * 3 + 0];
      cy = xb[a_idx * 3 + 1];
      cz = xb[a_idx * 3 + 2];
      srcSq = sq3_nofma(cx, cy, cz);

      if (htid < 64) {
        int cnt = 0;
        int first = 0;
        const unsigned long long below = ((unsigned long long)1 << htid) - 1ull;
        for (int chunk = 0; chunk < NPTS / 128; ++chunk) {
          const int n0 = (chunk << 7) + (htid << 1);       // 2 points per lane
          const float* p = xb + (size_t)n0 * 3;            // 24B-aligned
          const float2 A = *(const float2*)(p + 0);        // x0 y0
          const float2 Bv = *(const float2*)(p + 2);       // z0 x1
          const float2 C = *(const float2*)(p + 4);        // y1 z1
          const float x0 = A.x, y0 = A.y, z0 = Bv.x;
          const float x1 = Bv.y, y1 = C.x, z1 = C.y;

          const float sqr0 = ballquery_sqr(srcSq, sq3_nofma(x0, y0, z0),
                                           dot3_fma(cx, cy, cz, x0, y0, z0));
          const float sqr1 = ballquery_sqr(srcSq, sq3_nofma(x1, y1, z1),
                                           dot3_fma(cx, cy, cz, x1, y1, z1));
          const bool ok0 = !(sqr0 > R2);
          const bool ok1 = !(sqr1 > R2);
          const unsigned long long m0 = __ballot(ok0);
          const unsigned long long m1 = __ballot(ok1);
          if (cnt == 0 && (m0 | m1)) {
            const int f0 = m0 ? (int)__builtin_ctzll(m0) : 64;
            const int f1 = m1 ? (int)__builtin_ctzll(m1) : 64;
            first = (f0 <= f1) ? ((chunk << 7) + 2 * f0) : ((chunk << 7) + 2 * f1 + 1);
          }
          const int p0 = cnt + (int)__popcll(m0 & below) + (int)__popcll(m1 & below);
          const int p1 = p0 + (ok0 ? 1 : 0);
          if (ok0 && p0 < NK) s_idx2[h][p0] = n0;
          if (ok1 && p1 < NK) s_idx2[h][p1] = n0 + 1;
          cnt += (int)__popcll(m0) + (int)__popcll(m1);
          if (cnt >= NK) break;
        }
        if (htid >= cnt && htid < NK) s_idx2[h][htid] = first;  // pad with first in-radius
      }
    }
    __syncthreads();

    if (act) {
      // output 0: new_xyz (exact copy of the centroid row)
      if (htid == 0) {
        float* onx = out + (size_t)gb * 3;
        onx[0] = cx; onx[1] = cy; onx[2] = cz;
      }

      // output 1: rows [points[idx](128) | xyz[idx](3) | points[anchor](128)]
      float* op = out + (size_t)NBATCH * NGROUP * 3 + (size_t)gb * (NK * ROWLEN);
      const float* anchor = pb + (size_t)a_idx * NCH;

      // points part: 24 rows x 32 float4
#pragma unroll
      for (int it = 0; it < 3; ++it) {
        const int vidx = htid + (it << 8);
        const int k = vidx >> 5;
        const int c4 = vidx & 31;
        const int si = s_idx2[h][k];
        const f4s val = *(const f4s*)(pb + (size_t)si * NCH + (c4 << 2));
        *(f4s*)(op + k * ROWLEN + (c4 << 2)) = val;
      }
      // anchor part: 24 rows x 32 float4
#pragma unroll
      for (int it = 0; it < 3; ++it) {
        const int vidx = htid + (it << 8);
        const int k = vidx >> 5;
        const int c4 = vidx & 31;
        const f4s val = *(const f4s*)(anchor + (c4 << 2));
        *(f4s*)(op + k * ROWLEN + (NCH + 3) + (c4 << 2)) = val;
      }
      // xyz part: 24 rows x 3 floats
      if (htid < NK * 3) {
        const int k = htid / 3;
        const int r = htid - k * 3;
        const int si = s_idx2[h][k];
        op[k * ROWLEN + NCH + r] = xb[si * 3 + r];
      }
    }
    __syncthreads();   // protect s_idx2/s_aidx before next iteration
  }
}

extern "C" void kernel_launch(void* const* d_in, const int* in_sizes, int n_in,
                              void* d_out, int out_size, void* d_ws, size_t ws_size,
                              hipStream_t stream) {
  const float* xyz = (const float*)d_in[0];
  const float* points = (const float*)d_in[1];
  float* out = (float*)d_out;
  int* fps_idx = (int*)d_ws;  // 8*2048 ints

  // poison fps_idx to -1: the producer/consumer handshake sentinel
  hipMemsetAsync(d_ws, 0xFF, (size_t)NBATCH * NGROUP * sizeof(int), stream);
  fused_kernel<<<dim3(NBATCH + GBLOCKS), dim3(FPS_T), 0, stream>>>(xyz, points, fps_idx, out);
}